// Round 13
// baseline (485.661 us; speedup 1.0000x reference)
//
#include <hip/hip_runtime.h>
#include <cstdint>
#include <cstddef>

#define NNODES 100000
#define NEDGES 1600000
#define IN_DIM 20
#define HID    32
#define HEADS  4
#define HC1    128
#define OUTC   64
#define NEG    0.2f
#define LOG2E  1.4426950408889634f
#define NCHUNK ((NNODES + 255) / 256)   // 391
#define NBLK   ((NNODES + 63) / 64)     // 1563
#define EBLK   ((NEDGES + 255) / 256)   // 6250
#define PREPN  (16384 + 5120 + 128 + 64)
#define PBLK   ((PREPN + 255) / 256)    // 85

// clang-native packed half: arithmetic lowers to v_pk_*_f16
typedef _Float16 h2 __attribute__((ext_vector_type(2)));
typedef __fp16   hh2 __attribute__((ext_vector_type(2)));
typedef unsigned int uv4 __attribute__((ext_vector_type(4)));
typedef float fv4 __attribute__((ext_vector_type(4)));
union U4H { uint4 u; h2 h[4]; };
union U2H { uint2 u; h2 h[2]; };

#if __has_builtin(__builtin_amdgcn_fdot2)
#define FDOT2(a, b, c) __builtin_amdgcn_fdot2(__builtin_bit_cast(hh2, (a)), __builtin_bit_cast(hh2, (b)), (c), false)
#else
#define FDOT2(a, b, c) ((c) + (float)(a).x * (float)(b).x + (float)(a).y * (float)(b).y)
#endif

// ===== fused: edge histogram + erank + per-block ea partial sums + weight prep =====
__global__ void k_histsum(const int* __restrict__ ei, const float* __restrict__ ea,
                          int* __restrict__ cnt, int* __restrict__ erank,
                          float* __restrict__ easpart,
                          const float* __restrict__ Wl1, const float* __restrict__ Wr1,
                          float* __restrict__ Bt1,
                          const float* __restrict__ Wl2, const float* __restrict__ Wr2,
                          float* __restrict__ Bt2,
                          const float* __restrict__ We1, const float* __restrict__ att1,
                          _Float16* __restrict__ Weh1, _Float16* __restrict__ Ath1,
                          const float* __restrict__ We2, const float* __restrict__ att2,
                          _Float16* __restrict__ Weh2, _Float16* __restrict__ Ath2) {
    int blk = blockIdx.x;
    int tid = threadIdx.x;
    if (blk < EBLK) {
        int e = blk * 256 + tid;
        float v = 0.0f;
        if (e < NEDGES) {
            erank[e] = atomicAdd(&cnt[ei[NEDGES + e]], 1);
            v = ea[e];
        }
        #pragma unroll
        for (int off = 32; off > 0; off >>= 1) v += __shfl_down(v, off, 64);
        __shared__ float ws4[4];
        int lane = tid & 63, wid = tid >> 6;
        if (lane == 0) ws4[wid] = v;
        __syncthreads();
        if (tid == 0) easpart[blk] = ws4[0] + ws4[1] + ws4[2] + ws4[3];
    } else {
        int idx = (blk - EBLK) * 256 + tid;
        if (idx < 16384) {
            int k = idx >> 7, c = idx & 127;
            Bt2[idx] = (c < 64) ? Wl2[c * HC1 + k] : Wr2[(c - 64) * HC1 + k];
        }
        int i1 = idx - 16384;
        if (i1 >= 0 && i1 < 5120) {
            int k = i1 >> 8, c = i1 & 255;
            Bt1[i1] = (c < 128) ? Wl1[c * IN_DIM + k] : Wr1[(c - 128) * IN_DIM + k];
        }
        int i2 = idx - (16384 + 5120);
        if (i2 >= 0 && i2 < 128) {
            Weh1[i2] = (_Float16)We1[i2];
            Ath1[i2] = (_Float16)(att1[i2] * LOG2E);
        }
        int i3 = idx - (16384 + 5120 + 128);
        if (i3 >= 0 && i3 < 64) {
            Weh2[i3] = (_Float16)We2[i3];
            Ath2[i3] = (_Float16)(att2[i3] * LOG2E);
        }
    }
}

// ===== fused: chunk scan + degree histogram (cnt value IS the degree) =====
__global__ void k_scan_chunk(const int* __restrict__ cnt, int* __restrict__ rowptr,
                             int* __restrict__ csums,
                             int* __restrict__ bcnt, int* __restrict__ nrankp) {
    __shared__ int s[256];
    __shared__ int lcnt[64];
    __shared__ int lbase[64];
    int tid = threadIdx.x;
    if (tid < 64) lcnt[tid] = 0;
    int i = blockIdx.x * 256 + tid;
    int v = (i < NNODES) ? cnt[i] : 0;
    s[tid] = v;
    __syncthreads();
    for (int off = 1; off < 256; off <<= 1) {
        int t = (tid >= off) ? s[tid - off] : 0;
        __syncthreads();
        s[tid] += t;
        __syncthreads();
    }
    if (i < NNODES) rowptr[i] = s[tid] - v;
    if (tid == 255) csums[blockIdx.x] = s[255];
    int d = v > 63 ? 63 : v;
    int lr = 0;
    if (i < NNODES) lr = atomicAdd(&lcnt[d], 1);
    __syncthreads();
    if (tid < 64) lbase[tid] = lcnt[tid] ? atomicAdd(&bcnt[tid], lcnt[tid]) : 0;
    __syncthreads();
    if (i < NNODES) nrankp[i] = (d << 20) | (lbase[d] + lr);
}

// ===== fused: top-level scan + bucket-base scan + easum reduction =====
__global__ void k_scan_tops(int* __restrict__ csums,
                            const int* __restrict__ bcnt, int* __restrict__ bbase,
                            const float* __restrict__ easpart, float* __restrict__ easum) {
    __shared__ int s[512];
    __shared__ float fs[512];
    int tid = threadIdx.x;
    int v = (tid < NCHUNK) ? csums[tid] : 0;
    s[tid] = v;
    float sv = 0.0f;
    for (int i = tid; i < EBLK; i += 512) sv += easpart[i];
    fs[tid] = sv;
    __syncthreads();
    for (int off = 1; off < 512; off <<= 1) {
        int t = (tid >= off) ? s[tid - off] : 0;
        __syncthreads();
        s[tid] += t;
        __syncthreads();
    }
    if (tid < NCHUNK) csums[tid] = s[tid] - v;
    if (tid < 64) {
        int b = bcnt[tid];
        int sum = b;
        #pragma unroll
        for (int off = 1; off < 64; off <<= 1) {
            int t = __shfl_up(sum, off, 64);
            if (tid >= off) sum += t;
        }
        bbase[tid] = sum - b;
    }
    __syncthreads();
    for (int off = 256; off > 0; off >>= 1) {
        if (tid < off) fs[tid] += fs[tid + off];
        __syncthreads();
    }
    if (tid == 0) easum[0] = fs[0];
}

// ===== fused: rowptr finalize + perm placement =====
__global__ void k_scan_add(int* __restrict__ rowptr, const int* __restrict__ csums,
                           const int* __restrict__ nrankp, const int* __restrict__ bbase,
                           int* __restrict__ perm) {
    int i = blockIdx.x * 256 + threadIdx.x;
    if (i < NNODES) {
        rowptr[i] += csums[blockIdx.x];
        int np = nrankp[i];
        int d = np >> 20, r = np & 0xFFFFF;
        perm[bbase[d] + r] = i;
    }
    if (i == 0) rowptr[NNODES] = NEDGES;
}

// packed 4B edge descriptor: (src:17 | ea_fp16_positive:15)
__global__ void k_scatter(const int* __restrict__ ei, const float* __restrict__ ea,
                          const int* __restrict__ rowptr, const int* __restrict__ erank,
                          unsigned* __restrict__ cedge) {
    int e = blockIdx.x * blockDim.x + threadIdx.x;
    if (e >= NEDGES) return;
    int dst = ei[NEDGES + e];
    int pos = rowptr[dst] + erank[e];
    unsigned short hb = __builtin_bit_cast(unsigned short, (_Float16)ea[e]);
    cedge[pos] = ((unsigned)ei[e] << 15) | (unsigned)hb;
}

// ================= layer-1 GEMM: [N x 20] @ Bt1 -> xlh|xrh fp16 =================
__global__ __launch_bounds__(256) void k_gemm1(
        const float* __restrict__ x, const float* __restrict__ Bt,
        const float* __restrict__ bl, const float* __restrict__ br,
        _Float16* __restrict__ xlh, _Float16* __restrict__ xrh) {
    __shared__ float sA[64 * IN_DIM];
    __shared__ float sB[IN_DIM * 256];
    int nb = blockIdx.x * 64;
    int tid = threadIdx.x;
    {
        size_t base = (size_t)nb * IN_DIM;
        size_t maxf = (size_t)NNODES * IN_DIM;
        for (int f = tid * 4; f < 64 * IN_DIM; f += 1024) {
            float4 v;
            if (base + f + 4 <= maxf) v = *(const float4*)(x + base + f);
            else                      v = *(const float4*)(x + maxf - 4);
            *(float4*)(sA + f) = v;
        }
    }
    for (int f = tid * 4; f < IN_DIM * 256; f += 1024)
        *(float4*)(sB + f) = *(const float4*)(Bt + f);
    __syncthreads();

    int tn = tid & 7, tc = tid >> 3;
    float acc[8][8];
    #pragma unroll
    for (int i = 0; i < 8; ++i)
        #pragma unroll
        for (int c = 0; c < 8; ++c) acc[i][c] = 0.0f;

    #pragma unroll
    for (int kt = 0; kt < 5; ++kt) {
        float4 a[8], b0[4], b1[4];
        #pragma unroll
        for (int i = 0; i < 8; ++i)
            a[i] = *(const float4*)(sA + (tn + 8 * i) * IN_DIM + kt * 4);
        #pragma unroll
        for (int j = 0; j < 4; ++j) {
            b0[j] = *(const float4*)(sB + (kt * 4 + j) * 256 + tc * 8);
            b1[j] = *(const float4*)(sB + (kt * 4 + j) * 256 + tc * 8 + 4);
        }
        #pragma unroll
        for (int i = 0; i < 8; ++i) {
            const float* ap = (const float*)&a[i];
            #pragma unroll
            for (int j = 0; j < 4; ++j) {
                float av = ap[j];
                const float* p0 = (const float*)&b0[j];
                const float* p1 = (const float*)&b1[j];
                #pragma unroll
                for (int c = 0; c < 4; ++c) {
                    acc[i][c]     += av * p0[c];
                    acc[i][c + 4] += av * p1[c];
                }
            }
        }
    }
    int c0 = tc * 8;
    float4 bias0, bias1;
    if (c0 < 128) {
        bias0 = *(const float4*)(bl + c0);
        bias1 = *(const float4*)(bl + c0 + 4);
    } else {
        bias0 = *(const float4*)(br + c0 - 128);
        bias1 = *(const float4*)(br + c0 - 124);
    }
    const float* q0 = (const float*)&bias0;
    const float* q1 = (const float*)&bias1;
    #pragma unroll
    for (int i = 0; i < 8; ++i) {
        int n = nb + tn + 8 * i;
        if (n >= NNODES) continue;
        float w[8];
        #pragma unroll
        for (int c = 0; c < 4; ++c) { w[c] = acc[i][c] + q0[c]; w[c + 4] = acc[i][c + 4] + q1[c]; }
        U4H ph;
        #pragma unroll
        for (int c = 0; c < 4; ++c) {
            h2 t; t.x = (_Float16)w[2 * c]; t.y = (_Float16)w[2 * c + 1];
            ph.h[c] = t;
        }
        if (c0 < 128) *(uint4*)(xlh + (size_t)n * HC1 + c0)       = ph.u;
        else          *(uint4*)(xrh + (size_t)n * HC1 + c0 - 128) = ph.u;
    }
}

// ================= layer-2 GEMM: h1(fp16) @ Bt2 -> xl2h|xr2h fp16 ============
__global__ __launch_bounds__(256) void k_gemm2(
        const _Float16* __restrict__ h1h, const float* __restrict__ Bt,
        const float* __restrict__ bl, const float* __restrict__ br,
        _Float16* __restrict__ xl2h, _Float16* __restrict__ xr2h) {
    __shared__ float sA[64 * 132];
    __shared__ float sB[32 * 128];
    int nb = blockIdx.x * 64;
    int tid = threadIdx.x;
    for (int idx = tid * 8; idx < 64 * HC1; idx += 2048) {
        int node = idx >> 7, k = idx & 127;
        int gn = nb + node; if (gn >= NNODES) gn = NNODES - 1;
        U4H v; v.u = *(const uint4*)(h1h + ((size_t)gn << 7) + k);
        float4 f0, f1;
        f0.x = (float)v.h[0].x; f0.y = (float)v.h[0].y;
        f0.z = (float)v.h[1].x; f0.w = (float)v.h[1].y;
        f1.x = (float)v.h[2].x; f1.y = (float)v.h[2].y;
        f1.z = (float)v.h[3].x; f1.w = (float)v.h[3].y;
        *(float4*)(sA + node * 132 + k)     = f0;
        *(float4*)(sA + node * 132 + k + 4) = f1;
    }
    int tn = tid & 7, tc = tid >> 3;
    float acc[8][4];
    #pragma unroll
    for (int i = 0; i < 8; ++i)
        #pragma unroll
        for (int c = 0; c < 4; ++c) acc[i][c] = 0.0f;

    for (int kc = 0; kc < 4; ++kc) {
        __syncthreads();
        for (int f = tid * 4; f < 32 * 128; f += 1024)
            *(float4*)(sB + f) = *(const float4*)(Bt + kc * 4096 + f);
        __syncthreads();
        #pragma unroll
        for (int ks = 0; ks < 8; ++ks) {
            int k0 = kc * 32 + ks * 4;
            float4 a[8], b[4];
            #pragma unroll
            for (int i = 0; i < 8; ++i)
                a[i] = *(const float4*)(sA + (tn + 8 * i) * 132 + k0);
            #pragma unroll
            for (int j = 0; j < 4; ++j)
                b[j] = *(const float4*)(sB + (ks * 4 + j) * 128 + tc * 4);
            #pragma unroll
            for (int i = 0; i < 8; ++i) {
                const float* ap = (const float*)&a[i];
                #pragma unroll
                for (int j = 0; j < 4; ++j) {
                    float av = ap[j];
                    const float* bp = (const float*)&b[j];
                    #pragma unroll
                    for (int c = 0; c < 4; ++c) acc[i][c] += av * bp[c];
                }
            }
        }
    }
    int c0 = tc * 4;
    float4 bias;
    if (c0 < 64) bias = *(const float4*)(bl + c0);
    else         bias = *(const float4*)(br + c0 - 64);
    const float* q = (const float*)&bias;
    #pragma unroll
    for (int i = 0; i < 8; ++i) {
        int n = nb + tn + 8 * i;
        if (n >= NNODES) continue;
        float w[4];
        #pragma unroll
        for (int c = 0; c < 4; ++c) w[c] = acc[i][c] + q[c];
        U2H ph;
        h2 t0; t0.x = (_Float16)w[0]; t0.y = (_Float16)w[1];
        h2 t1; t1.x = (_Float16)w[2]; t1.y = (_Float16)w[3];
        ph.h[0] = t0; ph.h[1] = t1;
        if (c0 < 64) *(uint2*)(xl2h + (size_t)n * OUTC + c0)      = ph.u;
        else         *(uint2*)(xr2h + (size_t)n * OUTC + c0 - 64) = ph.u;
    }
}

// ===== fused per-node edge kernels: degree-balanced, fdot2, packed descriptors =====
// layer 1: 2 waves/node (channel halves = head pairs; per-head softmax is
// independent so halves never communicate). 8 edge-groups x 8 lanes.
__global__ __launch_bounds__(256) void k_node1(
        const int* __restrict__ perm,
        const int* __restrict__ rowptr, const unsigned* __restrict__ cedge,
        const float* __restrict__ easum,
        const _Float16* __restrict__ xlh, const _Float16* __restrict__ xrh,
        const _Float16* __restrict__ Weh, const _Float16* __restrict__ Ath,
        const float* __restrict__ bias, _Float16* __restrict__ h1h) {
    int slot = blockIdx.x * 4 + (threadIdx.x >> 6);
    if (slot >= 2 * NNODES) return;
    int n = perm[slot >> 1];
    int half = slot & 1;
    int lane = threadIdx.x & 63;
    int g = lane >> 3;            // edge slot 0..7
    int q = lane & 7;             // channel oct within half
    int ch = half * 64 + q * 8;   // global channel base (head = ch>>5)
    U4H xru; xru.u = *(const uint4*)(xrh + ((unsigned)n << 7) + ch);
    U4H weu; weu.u = *(const uint4*)(Weh + ch);
    U4H atu; atu.u = *(const uint4*)(Ath + ch);
    h2 neg2; neg2.x = (_Float16)NEG; neg2.y = neg2.x;
    h2 zero; zero.x = (_Float16)0; zero.y = zero.x;
    h2 acc2[4] = { zero, zero, zero, zero };
    float s = 0.0f;
    int start = rowptr[n], deg = rowptr[n + 1] - start;

    // ---- self edge (only group 0 contributes) ----
    {
        U4H xss; xss.u = *(const uint4*)(xlh + ((unsigned)n << 7) + ch);
        float amean = easum[0] * (1.0f / (float)NEDGES);
        h2 a2; a2.x = (_Float16)amean; a2.y = a2.x;
        float p = 0.0f;
        #pragma unroll
        for (int j = 0; j < 4; ++j) {
            h2 e = xss.h[j] + (a2 * weu.h[j] + xru.h[j]);
            h2 l = __builtin_elementwise_max(e, neg2 * e);
            p = FDOT2(l, atu.h[j], p);
        }
        p += __shfl_xor(p, 1, 64);
        p += __shfl_xor(p, 2, 64);   // head logit over 4-lane quad
        if (g == 0) {
            float pe = exp2f(p);
            s += pe;
            h2 pe2; pe2.x = (_Float16)pe; pe2.y = pe2.x;
            #pragma unroll
            for (int j = 0; j < 4; ++j) acc2[j] += pe2 * xss.h[j];
        }
    }

    // ---- main loop: 8 edges/iter; packed descriptor prefetched 1 iter ahead ----
    if (deg > 0) {
        int dm1 = deg - 1;
        unsigned ep = cedge[start + (g < dm1 ? g : dm1)];
        for (int base = 0; base < deg; base += 8) {
            unsigned cE = ep;
            int nxt = base + 8;
            if (nxt < deg) {
                int o = nxt + g;
                ep = cedge[start + (o < dm1 ? o : dm1)];
            }
            int src = cE >> 15;
            U4H xC; xC.u = *(const uint4*)(xlh + ((unsigned)src << 7) + ch);
            _Float16 av = __builtin_bit_cast(_Float16, (unsigned short)(cE & 0x7FFFu));
            h2 a2; a2.x = av; a2.y = av;
            float p = 0.0f;
            #pragma unroll
            for (int j = 0; j < 4; ++j) {
                h2 e = xC.h[j] + (a2 * weu.h[j] + xru.h[j]);
                h2 l = __builtin_elementwise_max(e, neg2 * e);
                p = FDOT2(l, atu.h[j], p);
            }
            p += __shfl_xor(p, 1, 64);
            p += __shfl_xor(p, 2, 64);
            float pe = (base + g < deg) ? exp2f(p) : 0.0f;
            s += pe;
            h2 pe2; pe2.x = (_Float16)pe; pe2.y = pe2.x;
            #pragma unroll
            for (int j = 0; j < 4; ++j) acc2[j] += pe2 * xC.h[j];
        }
    }
    // merge the 8 edge-groups (xor flips lane bits 3..5; channel bits preserved)
    #pragma unroll
    for (int off = 8; off <= 32; off <<= 1) {
        s += __shfl_xor(s, off, 64);
        #pragma unroll
        for (int j = 0; j < 4; ++j) {
            int lv = __builtin_bit_cast(int, acc2[j]);
            int t = __shfl_xor(lv, off, 64);
            acc2[j] += __builtin_bit_cast(h2, t);
        }
    }
    if (g == 0) {
        float inv = 1.0f / s;
        float4 bi0 = *(const float4*)(bias + ch), bi1 = *(const float4*)(bias + ch + 4);
        const float* bq0 = (const float*)&bi0;
        const float* bq1 = (const float*)&bi1;
        float o[8];
        #pragma unroll
        for (int j = 0; j < 4; ++j) {
            float bj0 = (j < 2) ? bq0[2 * j] : bq1[2 * j - 4];
            float bj1 = (j < 2) ? bq0[2 * j + 1] : bq1[2 * j - 3];
            o[2 * j]     = (float)acc2[j].x * inv + bj0;
            o[2 * j + 1] = (float)acc2[j].y * inv + bj1;
        }
        #pragma unroll
        for (int k = 0; k < 8; ++k) o[k] = o[k] > 0.0f ? o[k] : expm1f(o[k]);   // ELU
        U4H ph;
        #pragma unroll
        for (int k = 0; k < 4; ++k) {
            h2 t; t.x = (_Float16)o[2 * k]; t.y = (_Float16)o[2 * k + 1];
            ph.h[k] = t;
        }
        __builtin_nontemporal_store(__builtin_bit_cast(uv4, ph.u),
                                    (uv4*)(h1h + ((unsigned)n << 7) + ch));
    }
}

// layer 2: 1 wave/node (via perm), 8 edge-groups x 8 lanes; lane = 8 channels
__global__ __launch_bounds__(256) void k_node2(
        const int* __restrict__ perm,
        const int* __restrict__ rowptr, const unsigned* __restrict__ cedge,
        const float* __restrict__ easum,
        const _Float16* __restrict__ xl2h, const _Float16* __restrict__ xr2h,
        const _Float16* __restrict__ Weh, const _Float16* __restrict__ Ath,
        const float* __restrict__ bias, float* __restrict__ out) {
    int slot = blockIdx.x * 4 + (threadIdx.x >> 6);
    if (slot >= NNODES) return;
    int n = perm[slot];
    int lane = threadIdx.x & 63;
    int g = lane >> 3;        // edge slot 0..7
    int q = lane & 7;         // channel oct
    int c = q * 8;
    U4H xru; xru.u = *(const uint4*)(xr2h + ((unsigned)n << 6) + c);
    U4H weu; weu.u = *(const uint4*)(Weh + c);
    U4H atu; atu.u = *(const uint4*)(Ath + c);
    h2 neg2; neg2.x = (_Float16)NEG; neg2.y = neg2.x;
    h2 zero; zero.x = (_Float16)0; zero.y = zero.x;
    h2 acc2[4] = { zero, zero, zero, zero };
    float s = 0.0f;
    int start = rowptr[n], deg = rowptr[n + 1] - start;

    // ---- self edge ----
    {
        U4H xss; xss.u = *(const uint4*)(xl2h + ((unsigned)n << 6) + c);
        float amean = easum[0] * (1.0f / (float)NEDGES);
        h2 a2; a2.x = (_Float16)amean; a2.y = a2.x;
        float p = 0.0f;
        #pragma unroll
        for (int j = 0; j < 4; ++j) {
            h2 e = xss.h[j] + (a2 * weu.h[j] + xru.h[j]);
            h2 l = __builtin_elementwise_max(e, neg2 * e);
            p = FDOT2(l, atu.h[j], p);
        }
        p += __shfl_xor(p, 1, 64);
        p += __shfl_xor(p, 2, 64);
        p += __shfl_xor(p, 4, 64);
        if (g == 0) {
            float pe = exp2f(p);
            s += pe;
            h2 pe2; pe2.x = (_Float16)pe; pe2.y = pe2.x;
            #pragma unroll
            for (int j = 0; j < 4; ++j) acc2[j] += pe2 * xss.h[j];
        }
    }

    // ---- main loop: 8 edges/iter; packed descriptor prefetched 1 iter ahead ----
    if (deg > 0) {
        int dm1 = deg - 1;
        unsigned ep = cedge[start + (g < dm1 ? g : dm1)];
        for (int base = 0; base < deg; base += 8) {
            unsigned cE = ep;
            int nxt = base + 8;
            if (nxt < deg) {
                int o = nxt + g;
                ep = cedge[start + (o < dm1 ? o : dm1)];
            }
            int src = cE >> 15;
            U4H xC; xC.u = *(const uint4*)(xl2h + ((unsigned)src << 6) + c);
            _Float16 av = __builtin_bit_cast(_Float16, (unsigned short)(cE & 0x7FFFu));
            h2 a2; a2.x = av; a2.y = av;
            float p = 0.0f;
            #pragma unroll
            for (int j = 0; j < 4; ++j) {
                h2 e = xC.h[j] + (a2 * weu.h[j] + xru.h[j]);
                h2 l = __builtin_elementwise_max(e, neg2 * e);
                p = FDOT2(l, atu.h[j], p);
            }
            p += __shfl_xor(p, 1, 64);
            p += __shfl_xor(p, 2, 64);
            p += __shfl_xor(p, 4, 64);
            float pe = (base + g < deg) ? exp2f(p) : 0.0f;
            s += pe;
            h2 pe2; pe2.x = (_Float16)pe; pe2.y = pe2.x;
            #pragma unroll
            for (int j = 0; j < 4; ++j) acc2[j] += pe2 * xC.h[j];
        }
    }
    #pragma unroll
    for (int off = 8; off <= 32; off <<= 1) {
        s += __shfl_xor(s, off, 64);
        #pragma unroll
        for (int j = 0; j < 4; ++j) {
            int lv = __builtin_bit_cast(int, acc2[j]);
            int t = __shfl_xor(lv, off, 64);
            acc2[j] += __builtin_bit_cast(h2, t);
        }
    }
    if (g == 0) {
        float inv = 1.0f / s;
        float4 bi0 = *(const float4*)(bias + c), bi1 = *(const float4*)(bias + c + 4);
        const float* bq0 = (const float*)&bi0;
        const float* bq1 = (const float*)&bi1;
        fv4 o0, o1;
        o0.x = (float)acc2[0].x * inv + bq0[0];  o0.y = (float)acc2[0].y * inv + bq0[1];
        o0.z = (float)acc2[1].x * inv + bq0[2];  o0.w = (float)acc2[1].y * inv + bq0[3];
        o1.x = (float)acc2[2].x * inv + bq1[0];  o1.y = (float)acc2[2].y * inv + bq1[1];
        o1.z = (float)acc2[3].x * inv + bq1[2];  o1.w = (float)acc2[3].y * inv + bq1[3];
        float* op = out + (size_t)n * OUTC + c;
        __builtin_nontemporal_store(o0, (fv4*)op);
        __builtin_nontemporal_store(o1, (fv4*)(op + 4));
    }
}

extern "C" void kernel_launch(void* const* d_in, const int* in_sizes, int n_in,
                              void* d_out, int out_size, void* d_ws, size_t ws_size,
                              hipStream_t stream) {
    (void)in_sizes; (void)n_in; (void)out_size; (void)ws_size;
    const float* x    = (const float*)d_in[0];
    const int*   ei   = (const int*)d_in[1];
    const float* ea   = (const float*)d_in[2];
    const float* Wl1  = (const float*)d_in[3];
    const float* bl1  = (const float*)d_in[4];
    const float* Wr1  = (const float*)d_in[5];
    const float* br1  = (const float*)d_in[6];
    const float* We1  = (const float*)d_in[7];
    const float* att1 = (const float*)d_in[8];
    const float* b1   = (const float*)d_in[9];
    const float* Wl2  = (const float*)d_in[10];
    const float* bl2  = (const float*)d_in[11];
    const float* Wr2  = (const float*)d_in[12];
    const float* br2  = (const float*)d_in[13];
    const float* We2  = (const float*)d_in[14];
    const float* att2 = (const float*)d_in[15];
    const float* b2   = (const float*)d_in[16];
    float* out = (float*)d_out;

    // ---- workspace layout (bytes; every region 16B-aligned) ----
    char* wsb = (char*)d_ws;
    _Float16* xlh  = (_Float16*)wsb; wsb += (size_t)NNODES * HC1 * 2;   // 25.6 MB
    _Float16* xrh  = (_Float16*)wsb; wsb += (size_t)NNODES * HC1 * 2;
    _Float16* h1h  = (_Float16*)wsb; wsb += (size_t)NNODES * HC1 * 2;
    unsigned* cedge= (unsigned*)wsb; wsb += (size_t)NEDGES * 4;         // 6.4 MB packed
    int*    erank  = (int*)wsb;      wsb += (size_t)NEDGES * 4;         // 6.4 MB
    int*    nrankp = (int*)wsb;      wsb += (size_t)NNODES * 4;
    int*    rowptr = (int*)wsb;      wsb += ((size_t)(NNODES + 4) * 4);
    int*    perm   = (int*)wsb;      wsb += (size_t)NNODES * 4;
    int*    csums  = (int*)wsb;      wsb += 512 * 4;
    float*  easpart= (float*)wsb;    wsb += (size_t)EBLK * 4;
    // --- contiguous zero-init region: cnt | bcnt ---
    int*    cnt    = (int*)wsb;      wsb += (size_t)NNODES * 4;
    int*    bcnt   = (int*)wsb;      wsb += 64 * 4;
    size_t  zbytes = (size_t)NNODES * 4 + 64 * 4;
    // ---
    int*    bbase  = (int*)wsb;      wsb += 64 * 4;
    float*  easum  = (float*)wsb;    wsb += 16;
    float*  Bt1    = (float*)wsb;    wsb += 20 * 256 * 4;
    float*  Bt2    = (float*)wsb;    wsb += 128 * 128 * 4;
    _Float16* Weh1 = (_Float16*)wsb; wsb += 128 * 2;
    _Float16* Ath1 = (_Float16*)wsb; wsb += 128 * 2;
    _Float16* Weh2 = (_Float16*)wsb; wsb += 64 * 2;
    _Float16* Ath2 = (_Float16*)wsb; wsb += 64 * 2;
    _Float16* xl2h = xlh;   // layer-2 tables reuse layer-1 storage
    _Float16* xr2h = xrh;

    hipMemsetAsync(cnt, 0, zbytes, stream);

    // ---- fused CSR build + prep (5 kernels) ----
    k_histsum<<<EBLK + PBLK, 256, 0, stream>>>(ei, ea, cnt, erank, easpart,
        Wl1, Wr1, Bt1, Wl2, Wr2, Bt2, We1, att1, Weh1, Ath1, We2, att2, Weh2, Ath2);
    k_scan_chunk<<<NCHUNK, 256, 0, stream>>>(cnt, rowptr, csums, bcnt, nrankp);
    k_scan_tops<<<1, 512, 0, stream>>>(csums, bcnt, bbase, easpart, easum);
    k_scan_add<<<NCHUNK, 256, 0, stream>>>(rowptr, csums, nrankp, bbase, perm);
    k_scatter<<<(NEDGES + 255) / 256, 256, 0, stream>>>(ei, ea, rowptr, erank, cedge);

    // ---- layer 1 ----
    k_gemm1<<<NBLK, 256, 0, stream>>>(x, Bt1, bl1, br1, xlh, xrh);
    k_node1<<<(2 * NNODES + 3) / 4, 256, 0, stream>>>(perm, rowptr, cedge, easum,
                                                      xlh, xrh, Weh1, Ath1, b1, h1h);

    // ---- layer 2 ----
    k_gemm2<<<NBLK, 256, 0, stream>>>(h1h, Bt2, bl2, br2, xl2h, xr2h);
    k_node2<<<(NNODES + 3) / 4, 256, 0, stream>>>(perm, rowptr, cedge, easum,
                                                  xl2h, xr2h, Weh2, Ath2, b2, out);
}

// Round 14
// 453.096 us; speedup vs baseline: 1.0719x; 1.0719x over previous
//
#include <hip/hip_runtime.h>
#include <cstdint>
#include <cstddef>

#define NNODES 100000
#define NEDGES 1600000
#define IN_DIM 20
#define HID    32
#define HEADS  4
#define HC1    128
#define OUTC   64
#define NEG    0.2f
#define LOG2E  1.4426950408889634f
#define NCHUNK ((NNODES + 255) / 256)   // 391
#define NBLK   ((NNODES + 63) / 64)     // 1563
#define EBLK   ((NEDGES + 255) / 256)   // 6250
#define PREPN  (16384 + 5120 + 128 + 64)
#define PBLK   ((PREPN + 255) / 256)    // 85

// clang-native packed half: arithmetic lowers to v_pk_*_f16
typedef _Float16 h2 __attribute__((ext_vector_type(2)));
typedef __fp16   hh2 __attribute__((ext_vector_type(2)));
typedef float fv4 __attribute__((ext_vector_type(4)));
union U4H { uint4 u; h2 h[4]; };
union U2H { uint2 u; h2 h[2]; };

#if __has_builtin(__builtin_amdgcn_fdot2)
#define FDOT2(a, b, c) __builtin_amdgcn_fdot2(__builtin_bit_cast(hh2, (a)), __builtin_bit_cast(hh2, (b)), (c), false)
#else
#define FDOT2(a, b, c) ((c) + (float)(a).x * (float)(b).x + (float)(a).y * (float)(b).y)
#endif

// ===== fused: edge histogram + erank + per-block ea partial sums + weight prep =====
__global__ void k_histsum(const int* __restrict__ ei, const float* __restrict__ ea,
                          int* __restrict__ cnt, int* __restrict__ erank,
                          float* __restrict__ easpart,
                          const float* __restrict__ Wl1, const float* __restrict__ Wr1,
                          float* __restrict__ Bt1,
                          const float* __restrict__ Wl2, const float* __restrict__ Wr2,
                          float* __restrict__ Bt2,
                          const float* __restrict__ We1, const float* __restrict__ att1,
                          _Float16* __restrict__ Weh1, _Float16* __restrict__ Ath1,
                          const float* __restrict__ We2, const float* __restrict__ att2,
                          _Float16* __restrict__ Weh2, _Float16* __restrict__ Ath2) {
    int blk = blockIdx.x;
    int tid = threadIdx.x;
    if (blk < EBLK) {
        int e = blk * 256 + tid;
        float v = 0.0f;
        if (e < NEDGES) {
            erank[e] = atomicAdd(&cnt[ei[NEDGES + e]], 1);
            v = ea[e];
        }
        #pragma unroll
        for (int off = 32; off > 0; off >>= 1) v += __shfl_down(v, off, 64);
        __shared__ float ws4[4];
        int lane = tid & 63, wid = tid >> 6;
        if (lane == 0) ws4[wid] = v;
        __syncthreads();
        if (tid == 0) easpart[blk] = ws4[0] + ws4[1] + ws4[2] + ws4[3];
    } else {
        int idx = (blk - EBLK) * 256 + tid;
        if (idx < 16384) {
            int k = idx >> 7, c = idx & 127;
            Bt2[idx] = (c < 64) ? Wl2[c * HC1 + k] : Wr2[(c - 64) * HC1 + k];
        }
        int i1 = idx - 16384;
        if (i1 >= 0 && i1 < 5120) {
            int k = i1 >> 8, c = i1 & 255;
            Bt1[i1] = (c < 128) ? Wl1[c * IN_DIM + k] : Wr1[(c - 128) * IN_DIM + k];
        }
        int i2 = idx - (16384 + 5120);
        if (i2 >= 0 && i2 < 128) {
            Weh1[i2] = (_Float16)We1[i2];
            Ath1[i2] = (_Float16)(att1[i2] * LOG2E);
        }
        int i3 = idx - (16384 + 5120 + 128);
        if (i3 >= 0 && i3 < 64) {
            Weh2[i3] = (_Float16)We2[i3];
            Ath2[i3] = (_Float16)(att2[i3] * LOG2E);
        }
    }
}

// ===== fused: chunk scan + degree histogram (cnt value IS the degree) =====
__global__ void k_scan_chunk(const int* __restrict__ cnt, int* __restrict__ rowptr,
                             int* __restrict__ csums,
                             int* __restrict__ bcnt, int* __restrict__ nrankp) {
    __shared__ int s[256];
    __shared__ int lcnt[64];
    __shared__ int lbase[64];
    int tid = threadIdx.x;
    if (tid < 64) lcnt[tid] = 0;
    int i = blockIdx.x * 256 + tid;
    int v = (i < NNODES) ? cnt[i] : 0;
    s[tid] = v;
    __syncthreads();
    for (int off = 1; off < 256; off <<= 1) {
        int t = (tid >= off) ? s[tid - off] : 0;
        __syncthreads();
        s[tid] += t;
        __syncthreads();
    }
    if (i < NNODES) rowptr[i] = s[tid] - v;
    if (tid == 255) csums[blockIdx.x] = s[255];
    int d = v > 63 ? 63 : v;
    int lr = 0;
    if (i < NNODES) lr = atomicAdd(&lcnt[d], 1);
    __syncthreads();
    if (tid < 64) lbase[tid] = lcnt[tid] ? atomicAdd(&bcnt[tid], lcnt[tid]) : 0;
    __syncthreads();
    if (i < NNODES) nrankp[i] = (d << 20) | (lbase[d] + lr);
}

// ===== fused: top-level scan + bucket-base scan + easum reduction =====
__global__ void k_scan_tops(int* __restrict__ csums,
                            const int* __restrict__ bcnt, int* __restrict__ bbase,
                            const float* __restrict__ easpart, float* __restrict__ easum) {
    __shared__ int s[512];
    __shared__ float fs[512];
    int tid = threadIdx.x;
    int v = (tid < NCHUNK) ? csums[tid] : 0;
    s[tid] = v;
    float sv = 0.0f;
    for (int i = tid; i < EBLK; i += 512) sv += easpart[i];
    fs[tid] = sv;
    __syncthreads();
    for (int off = 1; off < 512; off <<= 1) {
        int t = (tid >= off) ? s[tid - off] : 0;
        __syncthreads();
        s[tid] += t;
        __syncthreads();
    }
    if (tid < NCHUNK) csums[tid] = s[tid] - v;
    if (tid < 64) {
        int b = bcnt[tid];
        int sum = b;
        #pragma unroll
        for (int off = 1; off < 64; off <<= 1) {
            int t = __shfl_up(sum, off, 64);
            if (tid >= off) sum += t;
        }
        bbase[tid] = sum - b;
    }
    __syncthreads();
    for (int off = 256; off > 0; off >>= 1) {
        if (tid < off) fs[tid] += fs[tid + off];
        __syncthreads();
    }
    if (tid == 0) easum[0] = fs[0];
}

// ===== fused: rowptr finalize + perm placement =====
__global__ void k_scan_add(int* __restrict__ rowptr, const int* __restrict__ csums,
                           const int* __restrict__ nrankp, const int* __restrict__ bbase,
                           int* __restrict__ perm) {
    int i = blockIdx.x * 256 + threadIdx.x;
    if (i < NNODES) {
        rowptr[i] += csums[blockIdx.x];
        int np = nrankp[i];
        int d = np >> 20, r = np & 0xFFFFF;
        perm[bbase[d] + r] = i;
    }
    if (i == 0) rowptr[NNODES] = NEDGES;
}

// packed 4B edge descriptor: (src:17 | ea_fp16_positive:15)
__global__ void k_scatter(const int* __restrict__ ei, const float* __restrict__ ea,
                          const int* __restrict__ rowptr, const int* __restrict__ erank,
                          unsigned* __restrict__ cedge) {
    int e = blockIdx.x * blockDim.x + threadIdx.x;
    if (e >= NEDGES) return;
    int dst = ei[NEDGES + e];
    int pos = rowptr[dst] + erank[e];
    unsigned short hb = __builtin_bit_cast(unsigned short, (_Float16)ea[e]);
    cedge[pos] = ((unsigned)ei[e] << 15) | (unsigned)hb;
}

// ================= layer-1 GEMM: [N x 20] @ Bt1 -> xlh|xrh fp16 =================
__global__ __launch_bounds__(256) void k_gemm1(
        const float* __restrict__ x, const float* __restrict__ Bt,
        const float* __restrict__ bl, const float* __restrict__ br,
        _Float16* __restrict__ xlh, _Float16* __restrict__ xrh) {
    __shared__ float sA[64 * IN_DIM];
    __shared__ float sB[IN_DIM * 256];
    int nb = blockIdx.x * 64;
    int tid = threadIdx.x;
    {
        size_t base = (size_t)nb * IN_DIM;
        size_t maxf = (size_t)NNODES * IN_DIM;
        for (int f = tid * 4; f < 64 * IN_DIM; f += 1024) {
            float4 v;
            if (base + f + 4 <= maxf) v = *(const float4*)(x + base + f);
            else                      v = *(const float4*)(x + maxf - 4);
            *(float4*)(sA + f) = v;
        }
    }
    for (int f = tid * 4; f < IN_DIM * 256; f += 1024)
        *(float4*)(sB + f) = *(const float4*)(Bt + f);
    __syncthreads();

    int tn = tid & 7, tc = tid >> 3;
    float acc[8][8];
    #pragma unroll
    for (int i = 0; i < 8; ++i)
        #pragma unroll
        for (int c = 0; c < 8; ++c) acc[i][c] = 0.0f;

    #pragma unroll
    for (int kt = 0; kt < 5; ++kt) {
        float4 a[8], b0[4], b1[4];
        #pragma unroll
        for (int i = 0; i < 8; ++i)
            a[i] = *(const float4*)(sA + (tn + 8 * i) * IN_DIM + kt * 4);
        #pragma unroll
        for (int j = 0; j < 4; ++j) {
            b0[j] = *(const float4*)(sB + (kt * 4 + j) * 256 + tc * 8);
            b1[j] = *(const float4*)(sB + (kt * 4 + j) * 256 + tc * 8 + 4);
        }
        #pragma unroll
        for (int i = 0; i < 8; ++i) {
            const float* ap = (const float*)&a[i];
            #pragma unroll
            for (int j = 0; j < 4; ++j) {
                float av = ap[j];
                const float* p0 = (const float*)&b0[j];
                const float* p1 = (const float*)&b1[j];
                #pragma unroll
                for (int c = 0; c < 4; ++c) {
                    acc[i][c]     += av * p0[c];
                    acc[i][c + 4] += av * p1[c];
                }
            }
        }
    }
    int c0 = tc * 8;
    float4 bias0, bias1;
    if (c0 < 128) {
        bias0 = *(const float4*)(bl + c0);
        bias1 = *(const float4*)(bl + c0 + 4);
    } else {
        bias0 = *(const float4*)(br + c0 - 128);
        bias1 = *(const float4*)(br + c0 - 124);
    }
    const float* q0 = (const float*)&bias0;
    const float* q1 = (const float*)&bias1;
    #pragma unroll
    for (int i = 0; i < 8; ++i) {
        int n = nb + tn + 8 * i;
        if (n >= NNODES) continue;
        float w[8];
        #pragma unroll
        for (int c = 0; c < 4; ++c) { w[c] = acc[i][c] + q0[c]; w[c + 4] = acc[i][c + 4] + q1[c]; }
        U4H ph;
        #pragma unroll
        for (int c = 0; c < 4; ++c) {
            h2 t; t.x = (_Float16)w[2 * c]; t.y = (_Float16)w[2 * c + 1];
            ph.h[c] = t;
        }
        if (c0 < 128) *(uint4*)(xlh + (size_t)n * HC1 + c0)       = ph.u;
        else          *(uint4*)(xrh + (size_t)n * HC1 + c0 - 128) = ph.u;
    }
}

// ================= layer-2 GEMM: h1(fp16) @ Bt2 -> xl2h|xr2h fp16 ============
__global__ __launch_bounds__(256) void k_gemm2(
        const _Float16* __restrict__ h1h, const float* __restrict__ Bt,
        const float* __restrict__ bl, const float* __restrict__ br,
        _Float16* __restrict__ xl2h, _Float16* __restrict__ xr2h) {
    __shared__ float sA[64 * 132];
    __shared__ float sB[32 * 128];
    int nb = blockIdx.x * 64;
    int tid = threadIdx.x;
    for (int idx = tid * 8; idx < 64 * HC1; idx += 2048) {
        int node = idx >> 7, k = idx & 127;
        int gn = nb + node; if (gn >= NNODES) gn = NNODES - 1;
        U4H v; v.u = *(const uint4*)(h1h + ((size_t)gn << 7) + k);
        float4 f0, f1;
        f0.x = (float)v.h[0].x; f0.y = (float)v.h[0].y;
        f0.z = (float)v.h[1].x; f0.w = (float)v.h[1].y;
        f1.x = (float)v.h[2].x; f1.y = (float)v.h[2].y;
        f1.z = (float)v.h[3].x; f1.w = (float)v.h[3].y;
        *(float4*)(sA + node * 132 + k)     = f0;
        *(float4*)(sA + node * 132 + k + 4) = f1;
    }
    int tn = tid & 7, tc = tid >> 3;
    float acc[8][4];
    #pragma unroll
    for (int i = 0; i < 8; ++i)
        #pragma unroll
        for (int c = 0; c < 4; ++c) acc[i][c] = 0.0f;

    for (int kc = 0; kc < 4; ++kc) {
        __syncthreads();
        for (int f = tid * 4; f < 32 * 128; f += 1024)
            *(float4*)(sB + f) = *(const float4*)(Bt + kc * 4096 + f);
        __syncthreads();
        #pragma unroll
        for (int ks = 0; ks < 8; ++ks) {
            int k0 = kc * 32 + ks * 4;
            float4 a[8], b[4];
            #pragma unroll
            for (int i = 0; i < 8; ++i)
                a[i] = *(const float4*)(sA + (tn + 8 * i) * 132 + k0);
            #pragma unroll
            for (int j = 0; j < 4; ++j)
                b[j] = *(const float4*)(sB + (ks * 4 + j) * 128 + tc * 4);
            #pragma unroll
            for (int i = 0; i < 8; ++i) {
                const float* ap = (const float*)&a[i];
                #pragma unroll
                for (int j = 0; j < 4; ++j) {
                    float av = ap[j];
                    const float* bp = (const float*)&b[j];
                    #pragma unroll
                    for (int c = 0; c < 4; ++c) acc[i][c] += av * bp[c];
                }
            }
        }
    }
    int c0 = tc * 4;
    float4 bias;
    if (c0 < 64) bias = *(const float4*)(bl + c0);
    else         bias = *(const float4*)(br + c0 - 64);
    const float* q = (const float*)&bias;
    #pragma unroll
    for (int i = 0; i < 8; ++i) {
        int n = nb + tn + 8 * i;
        if (n >= NNODES) continue;
        float w[4];
        #pragma unroll
        for (int c = 0; c < 4; ++c) w[c] = acc[i][c] + q[c];
        U2H ph;
        h2 t0; t0.x = (_Float16)w[0]; t0.y = (_Float16)w[1];
        h2 t1; t1.x = (_Float16)w[2]; t1.y = (_Float16)w[3];
        ph.h[0] = t0; ph.h[1] = t1;
        if (c0 < 64) *(uint2*)(xl2h + (size_t)n * OUTC + c0)      = ph.u;
        else         *(uint2*)(xr2h + (size_t)n * OUTC + c0 - 64) = ph.u;
    }
}

// ===== fused per-node edge kernels: R12 structure + packed 4B descriptors =====
// layer 1: 1 wave/node (via perm), 4 edge-groups x 16 lanes, 2-unrolled bodies
// (2 gathers in flight per wave — measured saturation point, see R9/R13).
__global__ __launch_bounds__(256) void k_node1(
        const int* __restrict__ perm,
        const int* __restrict__ rowptr, const unsigned* __restrict__ cedge,
        const float* __restrict__ easum,
        const _Float16* __restrict__ xlh, const _Float16* __restrict__ xrh,
        const _Float16* __restrict__ Weh, const _Float16* __restrict__ Ath,
        const float* __restrict__ bias, _Float16* __restrict__ h1h) {
    int slot = blockIdx.x * 4 + (threadIdx.x >> 6);
    if (slot >= NNODES) return;
    int n = perm[slot];
    int lane = threadIdx.x & 63;
    int g = lane >> 4;        // edge slot 0..3
    int q = lane & 15;        // channel oct; head = q>>2
    int c = q * 8;
    U4H xru; xru.u = *(const uint4*)(xrh + ((unsigned)n << 7) + c);
    U4H weu; weu.u = *(const uint4*)(Weh + c);
    U4H atu; atu.u = *(const uint4*)(Ath + c);   // att*log2e fp16
    h2 neg2; neg2.x = (_Float16)NEG; neg2.y = neg2.x;
    h2 zero; zero.x = (_Float16)0; zero.y = zero.x;
    h2 acc2[4] = { zero, zero, zero, zero };
    float s = 0.0f;
    int start = rowptr[n], deg = rowptr[n + 1] - start;

    // ---- self edge (prologue; only group 0 contributes) ----
    {
        U4H xss; xss.u = *(const uint4*)(xlh + ((unsigned)n << 7) + c);
        float amean = easum[0] * (1.0f / (float)NEDGES);
        h2 a2; a2.x = (_Float16)amean; a2.y = a2.x;
        float p = 0.0f;
        #pragma unroll
        for (int j = 0; j < 4; ++j) {
            h2 e = xss.h[j] + (a2 * weu.h[j] + xru.h[j]);
            h2 l = __builtin_elementwise_max(e, neg2 * e);
            p = FDOT2(l, atu.h[j], p);
        }
        p += __shfl_xor(p, 1, 64);
        p += __shfl_xor(p, 2, 64);
        if (g == 0) {
            float pe = exp2f(p);
            s += pe;
            h2 pe2; pe2.x = (_Float16)pe; pe2.y = pe2.x;
            #pragma unroll
            for (int j = 0; j < 4; ++j) acc2[j] += pe2 * xss.h[j];
        }
    }

    // ---- main loop: 8 edges/iter; descriptors prefetched 1 iter ahead ----
    if (deg > 0) {
        int dm1 = deg - 1;
        unsigned epA = cedge[start + (g < dm1 ? g : dm1)];
        unsigned epB = cedge[start + (4 + g < dm1 ? 4 + g : dm1)];
        for (int base = 0; base < deg; base += 8) {
            unsigned cA = epA, cB = epB;
            int nxt = base + 8;
            if (nxt < deg) {
                int oA = nxt + g, oB = nxt + 4 + g;
                epA = cedge[start + (oA < dm1 ? oA : dm1)];
                epB = cedge[start + (oB < dm1 ? oB : dm1)];
            }
            U4H xA; xA.u = *(const uint4*)(xlh + ((unsigned)(cA >> 15) << 7) + c);
            U4H xB; xB.u = *(const uint4*)(xlh + ((unsigned)(cB >> 15) << 7) + c);
            // edge A
            {
                _Float16 av = __builtin_bit_cast(_Float16, (unsigned short)(cA & 0x7FFFu));
                h2 a2; a2.x = av; a2.y = av;
                float p = 0.0f;
                #pragma unroll
                for (int j = 0; j < 4; ++j) {
                    h2 e = xA.h[j] + (a2 * weu.h[j] + xru.h[j]);
                    h2 l = __builtin_elementwise_max(e, neg2 * e);
                    p = FDOT2(l, atu.h[j], p);
                }
                p += __shfl_xor(p, 1, 64);
                p += __shfl_xor(p, 2, 64);
                float pe = (base + g < deg) ? exp2f(p) : 0.0f;
                s += pe;
                h2 pe2; pe2.x = (_Float16)pe; pe2.y = pe2.x;
                #pragma unroll
                for (int j = 0; j < 4; ++j) acc2[j] += pe2 * xA.h[j];
            }
            // edge B
            {
                _Float16 av = __builtin_bit_cast(_Float16, (unsigned short)(cB & 0x7FFFu));
                h2 a2; a2.x = av; a2.y = av;
                float p = 0.0f;
                #pragma unroll
                for (int j = 0; j < 4; ++j) {
                    h2 e = xB.h[j] + (a2 * weu.h[j] + xru.h[j]);
                    h2 l = __builtin_elementwise_max(e, neg2 * e);
                    p = FDOT2(l, atu.h[j], p);
                }
                p += __shfl_xor(p, 1, 64);
                p += __shfl_xor(p, 2, 64);
                float pe = (base + 4 + g < deg) ? exp2f(p) : 0.0f;
                s += pe;
                h2 pe2; pe2.x = (_Float16)pe; pe2.y = pe2.x;
                #pragma unroll
                for (int j = 0; j < 4; ++j) acc2[j] += pe2 * xB.h[j];
            }
        }
    }
    // merge the 4 edge-groups (plain sums; softmax shift-free)
    #pragma unroll
    for (int off = 16; off <= 32; off <<= 1) {
        s += __shfl_xor(s, off, 64);
        #pragma unroll
        for (int j = 0; j < 4; ++j) {
            int lv = __builtin_bit_cast(int, acc2[j]);
            int t = __shfl_xor(lv, off, 64);
            acc2[j] += __builtin_bit_cast(h2, t);
        }
    }
    if (g == 0) {
        float inv = 1.0f / s;
        float4 bi0 = *(const float4*)(bias + c), bi1 = *(const float4*)(bias + c + 4);
        const float* bq = (const float*)&bi0;
        const float* br_ = (const float*)&bi1;
        float o[8];
        #pragma unroll
        for (int j = 0; j < 4; ++j) {
            o[2 * j]     = (float)acc2[j].x * inv + (j < 2 ? bq[2 * j]     : br_[2 * j - 4]);
            o[2 * j + 1] = (float)acc2[j].y * inv + (j < 2 ? bq[2 * j + 1] : br_[2 * j - 3]);
        }
        #pragma unroll
        for (int k = 0; k < 8; ++k) o[k] = o[k] > 0.0f ? o[k] : expm1f(o[k]);   // ELU
        U4H ph;
        #pragma unroll
        for (int k = 0; k < 4; ++k) {
            h2 t; t.x = (_Float16)o[2 * k]; t.y = (_Float16)o[2 * k + 1];
            ph.h[k] = t;
        }
        *(uint4*)(h1h + ((unsigned)n << 7) + c) = ph.u;   // normal store: gemm2 re-reads via L2
    }
}

// layer 2: 1 wave/node (via perm), 8 edge-groups x 8 lanes; lane = 8 channels
__global__ __launch_bounds__(256) void k_node2(
        const int* __restrict__ perm,
        const int* __restrict__ rowptr, const unsigned* __restrict__ cedge,
        const float* __restrict__ easum,
        const _Float16* __restrict__ xl2h, const _Float16* __restrict__ xr2h,
        const _Float16* __restrict__ Weh, const _Float16* __restrict__ Ath,
        const float* __restrict__ bias, float* __restrict__ out) {
    int slot = blockIdx.x * 4 + (threadIdx.x >> 6);
    if (slot >= NNODES) return;
    int n = perm[slot];
    int lane = threadIdx.x & 63;
    int g = lane >> 3;        // edge slot 0..7
    int q = lane & 7;         // channel oct
    int c = q * 8;
    U4H xru; xru.u = *(const uint4*)(xr2h + ((unsigned)n << 6) + c);
    U4H weu; weu.u = *(const uint4*)(Weh + c);
    U4H atu; atu.u = *(const uint4*)(Ath + c);
    h2 neg2; neg2.x = (_Float16)NEG; neg2.y = neg2.x;
    h2 zero; zero.x = (_Float16)0; zero.y = zero.x;
    h2 acc2[4] = { zero, zero, zero, zero };
    float s = 0.0f;
    int start = rowptr[n], deg = rowptr[n + 1] - start;

    // ---- self edge ----
    {
        U4H xss; xss.u = *(const uint4*)(xl2h + ((unsigned)n << 6) + c);
        float amean = easum[0] * (1.0f / (float)NEDGES);
        h2 a2; a2.x = (_Float16)amean; a2.y = a2.x;
        float p = 0.0f;
        #pragma unroll
        for (int j = 0; j < 4; ++j) {
            h2 e = xss.h[j] + (a2 * weu.h[j] + xru.h[j]);
            h2 l = __builtin_elementwise_max(e, neg2 * e);
            p = FDOT2(l, atu.h[j], p);
        }
        p += __shfl_xor(p, 1, 64);
        p += __shfl_xor(p, 2, 64);
        p += __shfl_xor(p, 4, 64);
        if (g == 0) {
            float pe = exp2f(p);
            s += pe;
            h2 pe2; pe2.x = (_Float16)pe; pe2.y = pe2.x;
            #pragma unroll
            for (int j = 0; j < 4; ++j) acc2[j] += pe2 * xss.h[j];
        }
    }

    // ---- main loop: 8 edges/iter; packed descriptor prefetched 1 iter ahead ----
    if (deg > 0) {
        int dm1 = deg - 1;
        unsigned ep = cedge[start + (g < dm1 ? g : dm1)];
        for (int base = 0; base < deg; base += 8) {
            unsigned cE = ep;
            int nxt = base + 8;
            if (nxt < deg) {
                int o = nxt + g;
                ep = cedge[start + (o < dm1 ? o : dm1)];
            }
            U4H xC; xC.u = *(const uint4*)(xl2h + ((unsigned)(cE >> 15) << 6) + c);
            _Float16 av = __builtin_bit_cast(_Float16, (unsigned short)(cE & 0x7FFFu));
            h2 a2; a2.x = av; a2.y = av;
            float p = 0.0f;
            #pragma unroll
            for (int j = 0; j < 4; ++j) {
                h2 e = xC.h[j] + (a2 * weu.h[j] + xru.h[j]);
                h2 l = __builtin_elementwise_max(e, neg2 * e);
                p = FDOT2(l, atu.h[j], p);
            }
            p += __shfl_xor(p, 1, 64);
            p += __shfl_xor(p, 2, 64);
            p += __shfl_xor(p, 4, 64);
            float pe = (base + g < deg) ? exp2f(p) : 0.0f;
            s += pe;
            h2 pe2; pe2.x = (_Float16)pe; pe2.y = pe2.x;
            #pragma unroll
            for (int j = 0; j < 4; ++j) acc2[j] += pe2 * xC.h[j];
        }
    }
    #pragma unroll
    for (int off = 8; off <= 32; off <<= 1) {
        s += __shfl_xor(s, off, 64);
        #pragma unroll
        for (int j = 0; j < 4; ++j) {
            int lv = __builtin_bit_cast(int, acc2[j]);
            int t = __shfl_xor(lv, off, 64);
            acc2[j] += __builtin_bit_cast(h2, t);
        }
    }
    if (g == 0) {
        float inv = 1.0f / s;
        float4 bi0 = *(const float4*)(bias + c), bi1 = *(const float4*)(bias + c + 4);
        const float* bq0 = (const float*)&bi0;
        const float* bq1 = (const float*)&bi1;
        fv4 o0, o1;
        o0.x = (float)acc2[0].x * inv + bq0[0];  o0.y = (float)acc2[0].y * inv + bq0[1];
        o0.z = (float)acc2[1].x * inv + bq0[2];  o0.w = (float)acc2[1].y * inv + bq0[3];
        o1.x = (float)acc2[2].x * inv + bq1[0];  o1.y = (float)acc2[2].y * inv + bq1[1];
        o1.z = (float)acc2[3].x * inv + bq1[2];  o1.w = (float)acc2[3].y * inv + bq1[3];
        float* op = out + (size_t)n * OUTC + c;
        __builtin_nontemporal_store(o0, (fv4*)op);      // out is never re-read on device
        __builtin_nontemporal_store(o1, (fv4*)(op + 4));
    }
}

extern "C" void kernel_launch(void* const* d_in, const int* in_sizes, int n_in,
                              void* d_out, int out_size, void* d_ws, size_t ws_size,
                              hipStream_t stream) {
    (void)in_sizes; (void)n_in; (void)out_size; (void)ws_size;
    const float* x    = (const float*)d_in[0];
    const int*   ei   = (const int*)d_in[1];
    const float* ea   = (const float*)d_in[2];
    const float* Wl1  = (const float*)d_in[3];
    const float* bl1  = (const float*)d_in[4];
    const float* Wr1  = (const float*)d_in[5];
    const float* br1  = (const float*)d_in[6];
    const float* We1  = (const float*)d_in[7];
    const float* att1 = (const float*)d_in[8];
    const float* b1   = (const float*)d_in[9];
    const float* Wl2  = (const float*)d_in[10];
    const float* bl2  = (const float*)d_in[11];
    const float* Wr2  = (const float*)d_in[12];
    const float* br2  = (const float*)d_in[13];
    const float* We2  = (const float*)d_in[14];
    const float* att2 = (const float*)d_in[15];
    const float* b2   = (const float*)d_in[16];
    float* out = (float*)d_out;

    // ---- workspace layout (bytes; every region 16B-aligned) ----
    char* wsb = (char*)d_ws;
    _Float16* xlh  = (_Float16*)wsb; wsb += (size_t)NNODES * HC1 * 2;   // 25.6 MB
    _Float16* xrh  = (_Float16*)wsb; wsb += (size_t)NNODES * HC1 * 2;
    _Float16* h1h  = (_Float16*)wsb; wsb += (size_t)NNODES * HC1 * 2;
    unsigned* cedge= (unsigned*)wsb; wsb += (size_t)NEDGES * 4;         // 6.4 MB packed
    int*    erank  = (int*)wsb;      wsb += (size_t)NEDGES * 4;         // 6.4 MB
    int*    nrankp = (int*)wsb;      wsb += (size_t)NNODES * 4;
    int*    rowptr = (int*)wsb;      wsb += ((size_t)(NNODES + 4) * 4);
    int*    perm   = (int*)wsb;      wsb += (size_t)NNODES * 4;
    int*    csums  = (int*)wsb;      wsb += 512 * 4;
    float*  easpart= (float*)wsb;    wsb += (size_t)EBLK * 4;
    // --- contiguous zero-init region: cnt | bcnt ---
    int*    cnt    = (int*)wsb;      wsb += (size_t)NNODES * 4;
    int*    bcnt   = (int*)wsb;      wsb += 64 * 4;
    size_t  zbytes = (size_t)NNODES * 4 + 64 * 4;
    // ---
    int*    bbase  = (int*)wsb;      wsb += 64 * 4;
    float*  easum  = (float*)wsb;    wsb += 16;
    float*  Bt1    = (float*)wsb;    wsb += 20 * 256 * 4;
    float*  Bt2    = (float*)wsb;    wsb += 128 * 128 * 4;
    _Float16* Weh1 = (_Float16*)wsb; wsb += 128 * 2;
    _Float16* Ath1 = (_Float16*)wsb; wsb += 128 * 2;
    _Float16* Weh2 = (_Float16*)wsb; wsb += 64 * 2;
    _Float16* Ath2 = (_Float16*)wsb; wsb += 64 * 2;
    _Float16* xl2h = xlh;   // layer-2 tables reuse layer-1 storage
    _Float16* xr2h = xrh;

    hipMemsetAsync(cnt, 0, zbytes, stream);

    // ---- fused CSR build + prep (5 kernels) ----
    k_histsum<<<EBLK + PBLK, 256, 0, stream>>>(ei, ea, cnt, erank, easpart,
        Wl1, Wr1, Bt1, Wl2, Wr2, Bt2, We1, att1, Weh1, Ath1, We2, att2, Weh2, Ath2);
    k_scan_chunk<<<NCHUNK, 256, 0, stream>>>(cnt, rowptr, csums, bcnt, nrankp);
    k_scan_tops<<<1, 512, 0, stream>>>(csums, bcnt, bbase, easpart, easum);
    k_scan_add<<<NCHUNK, 256, 0, stream>>>(rowptr, csums, nrankp, bbase, perm);
    k_scatter<<<(NEDGES + 255) / 256, 256, 0, stream>>>(ei, ea, rowptr, erank, cedge);

    // ---- layer 1 ----
    k_gemm1<<<NBLK, 256, 0, stream>>>(x, Bt1, bl1, br1, xlh, xrh);
    k_node1<<<(NNODES + 3) / 4, 256, 0, stream>>>(perm, rowptr, cedge, easum,
                                                  xlh, xrh, Weh1, Ath1, b1, h1h);

    // ---- layer 2 ----
    k_gemm2<<<NBLK, 256, 0, stream>>>(h1h, Bt2, bl2, br2, xl2h, xr2h);
    k_node2<<<(NNODES + 3) / 4, 256, 0, stream>>>(perm, rowptr, cedge, easum,
                                                  xl2h, xr2h, Weh2, Ath2, b2, out);
}

// Round 16
// 442.265 us; speedup vs baseline: 1.0981x; 1.0245x over previous
//
#include <hip/hip_runtime.h>
#include <cstdint>
#include <cstddef>

#define NNODES 100000
#define NEDGES 1600000
#define IN_DIM 20
#define HID    32
#define HEADS  4
#define HC1    128
#define OUTC   64
#define NEG    0.2f
#define LOG2E  1.4426950408889634f
#define NCHUNK ((NNODES + 255) / 256)   // 391
#define NBLK   ((NNODES + 63) / 64)     // 1563
#define EBLK   ((NEDGES + 255) / 256)   // 6250
#define PREPN  (16384 + 5120 + 128 + 64)
#define PBLK   ((PREPN + 255) / 256)    // 85

// clang-native packed half: arithmetic lowers to v_pk_*_f16
typedef _Float16 h2 __attribute__((ext_vector_type(2)));
typedef __fp16   hh2 __attribute__((ext_vector_type(2)));
union U4H { uint4 u; h2 h[4]; };
union U2H { uint2 u; h2 h[2]; };

#if __has_builtin(__builtin_amdgcn_fdot2)
#define FDOT2(a, b, c) __builtin_amdgcn_fdot2(__builtin_bit_cast(hh2, (a)), __builtin_bit_cast(hh2, (b)), (c), false)
#else
#define FDOT2(a, b, c) ((c) + (float)(a).x * (float)(b).x + (float)(a).y * (float)(b).y)
#endif

// ===== fused: edge histogram + erank + per-block ea partial sums + weight prep =====
__global__ void k_histsum(const int* __restrict__ ei, const float* __restrict__ ea,
                          int* __restrict__ cnt, int* __restrict__ erank,
                          float* __restrict__ easpart,
                          const float* __restrict__ Wl1, const float* __restrict__ Wr1,
                          float* __restrict__ Bt1,
                          const float* __restrict__ Wl2, const float* __restrict__ Wr2,
                          float* __restrict__ Bt2,
                          const float* __restrict__ We1, const float* __restrict__ att1,
                          _Float16* __restrict__ Weh1, _Float16* __restrict__ Ath1,
                          const float* __restrict__ We2, const float* __restrict__ att2,
                          _Float16* __restrict__ Weh2, _Float16* __restrict__ Ath2) {
    int blk = blockIdx.x;
    int tid = threadIdx.x;
    if (blk < EBLK) {
        int e = blk * 256 + tid;
        float v = 0.0f;
        if (e < NEDGES) {
            erank[e] = atomicAdd(&cnt[ei[NEDGES + e]], 1);
            v = ea[e];
        }
        #pragma unroll
        for (int off = 32; off > 0; off >>= 1) v += __shfl_down(v, off, 64);
        __shared__ float ws4[4];
        int lane = tid & 63, wid = tid >> 6;
        if (lane == 0) ws4[wid] = v;
        __syncthreads();
        if (tid == 0) easpart[blk] = ws4[0] + ws4[1] + ws4[2] + ws4[3];
    } else {
        int idx = (blk - EBLK) * 256 + tid;
        if (idx < 16384) {
            int k = idx >> 7, c = idx & 127;
            Bt2[idx] = (c < 64) ? Wl2[c * HC1 + k] : Wr2[(c - 64) * HC1 + k];
        }
        int i1 = idx - 16384;
        if (i1 >= 0 && i1 < 5120) {
            int k = i1 >> 8, c = i1 & 255;
            Bt1[i1] = (c < 128) ? Wl1[c * IN_DIM + k] : Wr1[(c - 128) * IN_DIM + k];
        }
        int i2 = idx - (16384 + 5120);
        if (i2 >= 0 && i2 < 128) {
            Weh1[i2] = (_Float16)We1[i2];
            Ath1[i2] = (_Float16)(att1[i2] * LOG2E);
        }
        int i3 = idx - (16384 + 5120 + 128);
        if (i3 >= 0 && i3 < 64) {
            Weh2[i3] = (_Float16)We2[i3];
            Ath2[i3] = (_Float16)(att2[i3] * LOG2E);
        }
    }
}

// ===== fused: chunk scan + degree histogram (cnt value IS the degree) =====
__global__ void k_scan_chunk(const int* __restrict__ cnt, int* __restrict__ rowptr,
                             int* __restrict__ csums,
                             int* __restrict__ bcnt, int* __restrict__ nrankp) {
    __shared__ int s[256];
    __shared__ int lcnt[64];
    __shared__ int lbase[64];
    int tid = threadIdx.x;
    if (tid < 64) lcnt[tid] = 0;
    int i = blockIdx.x * 256 + tid;
    int v = (i < NNODES) ? cnt[i] : 0;
    s[tid] = v;
    __syncthreads();
    for (int off = 1; off < 256; off <<= 1) {
        int t = (tid >= off) ? s[tid - off] : 0;
        __syncthreads();
        s[tid] += t;
        __syncthreads();
    }
    if (i < NNODES) rowptr[i] = s[tid] - v;
    if (tid == 255) csums[blockIdx.x] = s[255];
    int d = v > 63 ? 63 : v;
    int lr = 0;
    if (i < NNODES) lr = atomicAdd(&lcnt[d], 1);
    __syncthreads();
    if (tid < 64) lbase[tid] = lcnt[tid] ? atomicAdd(&bcnt[tid], lcnt[tid]) : 0;
    __syncthreads();
    if (i < NNODES) nrankp[i] = (d << 20) | (lbase[d] + lr);
}

// ===== fused: top-level scan + bucket-base scan + easum reduction =====
__global__ void k_scan_tops(int* __restrict__ csums,
                            const int* __restrict__ bcnt, int* __restrict__ bbase,
                            const float* __restrict__ easpart, float* __restrict__ easum) {
    __shared__ int s[512];
    __shared__ float fs[512];
    int tid = threadIdx.x;
    int v = (tid < NCHUNK) ? csums[tid] : 0;
    s[tid] = v;
    float sv = 0.0f;
    for (int i = tid; i < EBLK; i += 512) sv += easpart[i];
    fs[tid] = sv;
    __syncthreads();
    for (int off = 1; off < 512; off <<= 1) {
        int t = (tid >= off) ? s[tid - off] : 0;
        __syncthreads();
        s[tid] += t;
        __syncthreads();
    }
    if (tid < NCHUNK) csums[tid] = s[tid] - v;
    if (tid < 64) {
        int b = bcnt[tid];
        int sum = b;
        #pragma unroll
        for (int off = 1; off < 64; off <<= 1) {
            int t = __shfl_up(sum, off, 64);
            if (tid >= off) sum += t;
        }
        bbase[tid] = sum - b;
    }
    __syncthreads();
    for (int off = 256; off > 0; off >>= 1) {
        if (tid < off) fs[tid] += fs[tid + off];
        __syncthreads();
    }
    if (tid == 0) easum[0] = fs[0];
}

// ===== fused: rowptr finalize + perm placement =====
__global__ void k_scan_add(int* __restrict__ rowptr, const int* __restrict__ csums,
                           const int* __restrict__ nrankp, const int* __restrict__ bbase,
                           int* __restrict__ perm) {
    int i = blockIdx.x * 256 + threadIdx.x;
    if (i < NNODES) {
        rowptr[i] += csums[blockIdx.x];
        int np = nrankp[i];
        int d = np >> 20, r = np & 0xFFFFF;
        perm[bbase[d] + r] = i;
    }
    if (i == 0) rowptr[NNODES] = NEDGES;
}

__global__ void k_scatter(const int* __restrict__ ei, const float* __restrict__ ea,
                          const int* __restrict__ rowptr, const int* __restrict__ erank,
                          int2* __restrict__ cedge) {
    int e = blockIdx.x * blockDim.x + threadIdx.x;
    if (e >= NEDGES) return;
    int dst = ei[NEDGES + e];
    int pos = rowptr[dst] + erank[e];
    cedge[pos] = make_int2(ei[e], __float_as_int(ea[e]));
}

// ================= layer-1 GEMM: [N x 20] @ Bt1 -> xlh|xrh fp16 =================
__global__ __launch_bounds__(256) void k_gemm1(
        const float* __restrict__ x, const float* __restrict__ Bt,
        const float* __restrict__ bl, const float* __restrict__ br,
        _Float16* __restrict__ xlh, _Float16* __restrict__ xrh) {
    __shared__ float sA[64 * IN_DIM];
    __shared__ float sB[IN_DIM * 256];
    int nb = blockIdx.x * 64;
    int tid = threadIdx.x;
    {
        size_t base = (size_t)nb * IN_DIM;
        size_t maxf = (size_t)NNODES * IN_DIM;
        for (int f = tid * 4; f < 64 * IN_DIM; f += 1024) {
            float4 v;
            if (base + f + 4 <= maxf) v = *(const float4*)(x + base + f);
            else                      v = *(const float4*)(x + maxf - 4);
            *(float4*)(sA + f) = v;
        }
    }
    for (int f = tid * 4; f < IN_DIM * 256; f += 1024)
        *(float4*)(sB + f) = *(const float4*)(Bt + f);
    __syncthreads();

    int tn = tid & 7, tc = tid >> 3;
    float acc[8][8];
    #pragma unroll
    for (int i = 0; i < 8; ++i)
        #pragma unroll
        for (int c = 0; c < 8; ++c) acc[i][c] = 0.0f;

    #pragma unroll
    for (int kt = 0; kt < 5; ++kt) {
        float4 a[8], b0[4], b1[4];
        #pragma unroll
        for (int i = 0; i < 8; ++i)
            a[i] = *(const float4*)(sA + (tn + 8 * i) * IN_DIM + kt * 4);
        #pragma unroll
        for (int j = 0; j < 4; ++j) {
            b0[j] = *(const float4*)(sB + (kt * 4 + j) * 256 + tc * 8);
            b1[j] = *(const float4*)(sB + (kt * 4 + j) * 256 + tc * 8 + 4);
        }
        #pragma unroll
        for (int i = 0; i < 8; ++i) {
            const float* ap = (const float*)&a[i];
            #pragma unroll
            for (int j = 0; j < 4; ++j) {
                float av = ap[j];
                const float* p0 = (const float*)&b0[j];
                const float* p1 = (const float*)&b1[j];
                #pragma unroll
                for (int c = 0; c < 4; ++c) {
                    acc[i][c]     += av * p0[c];
                    acc[i][c + 4] += av * p1[c];
                }
            }
        }
    }
    int c0 = tc * 8;
    float4 bias0, bias1;
    if (c0 < 128) {
        bias0 = *(const float4*)(bl + c0);
        bias1 = *(const float4*)(bl + c0 + 4);
    } else {
        bias0 = *(const float4*)(br + c0 - 128);
        bias1 = *(const float4*)(br + c0 - 124);
    }
    const float* q0 = (const float*)&bias0;
    const float* q1 = (const float*)&bias1;
    #pragma unroll
    for (int i = 0; i < 8; ++i) {
        int n = nb + tn + 8 * i;
        if (n >= NNODES) continue;
        float w[8];
        #pragma unroll
        for (int c = 0; c < 4; ++c) { w[c] = acc[i][c] + q0[c]; w[c + 4] = acc[i][c + 4] + q1[c]; }
        U4H ph;
        #pragma unroll
        for (int c = 0; c < 4; ++c) {
            h2 t; t.x = (_Float16)w[2 * c]; t.y = (_Float16)w[2 * c + 1];
            ph.h[c] = t;
        }
        if (c0 < 128) *(uint4*)(xlh + (size_t)n * HC1 + c0)       = ph.u;
        else          *(uint4*)(xrh + (size_t)n * HC1 + c0 - 128) = ph.u;
    }
}

// ================= layer-2 GEMM: h1(fp16) @ Bt2 -> xl2h|xr2h fp16 ============
__global__ __launch_bounds__(256) void k_gemm2(
        const _Float16* __restrict__ h1h, const float* __restrict__ Bt,
        const float* __restrict__ bl, const float* __restrict__ br,
        _Float16* __restrict__ xl2h, _Float16* __restrict__ xr2h) {
    __shared__ float sA[64 * 132];
    __shared__ float sB[32 * 128];
    int nb = blockIdx.x * 64;
    int tid = threadIdx.x;
    for (int idx = tid * 8; idx < 64 * HC1; idx += 2048) {
        int node = idx >> 7, k = idx & 127;
        int gn = nb + node; if (gn >= NNODES) gn = NNODES - 1;
        U4H v; v.u = *(const uint4*)(h1h + ((size_t)gn << 7) + k);
        float4 f0, f1;
        f0.x = (float)v.h[0].x; f0.y = (float)v.h[0].y;
        f0.z = (float)v.h[1].x; f0.w = (float)v.h[1].y;
        f1.x = (float)v.h[2].x; f1.y = (float)v.h[2].y;
        f1.z = (float)v.h[3].x; f1.w = (float)v.h[3].y;
        *(float4*)(sA + node * 132 + k)     = f0;
        *(float4*)(sA + node * 132 + k + 4) = f1;
    }
    int tn = tid & 7, tc = tid >> 3;
    float acc[8][4];
    #pragma unroll
    for (int i = 0; i < 8; ++i)
        #pragma unroll
        for (int c = 0; c < 4; ++c) acc[i][c] = 0.0f;

    for (int kc = 0; kc < 4; ++kc) {
        __syncthreads();
        for (int f = tid * 4; f < 32 * 128; f += 1024)
            *(float4*)(sB + f) = *(const float4*)(Bt + kc * 4096 + f);
        __syncthreads();
        #pragma unroll
        for (int ks = 0; ks < 8; ++ks) {
            int k0 = kc * 32 + ks * 4;
            float4 a[8], b[4];
            #pragma unroll
            for (int i = 0; i < 8; ++i)
                a[i] = *(const float4*)(sA + (tn + 8 * i) * 132 + k0);
            #pragma unroll
            for (int j = 0; j < 4; ++j)
                b[j] = *(const float4*)(sB + (ks * 4 + j) * 128 + tc * 4);
            #pragma unroll
            for (int i = 0; i < 8; ++i) {
                const float* ap = (const float*)&a[i];
                #pragma unroll
                for (int j = 0; j < 4; ++j) {
                    float av = ap[j];
                    const float* bp = (const float*)&b[j];
                    #pragma unroll
                    for (int c = 0; c < 4; ++c) acc[i][c] += av * bp[c];
                }
            }
        }
    }
    int c0 = tc * 4;
    float4 bias;
    if (c0 < 64) bias = *(const float4*)(bl + c0);
    else         bias = *(const float4*)(br + c0 - 64);
    const float* q = (const float*)&bias;
    #pragma unroll
    for (int i = 0; i < 8; ++i) {
        int n = nb + tn + 8 * i;
        if (n >= NNODES) continue;
        float w[4];
        #pragma unroll
        for (int c = 0; c < 4; ++c) w[c] = acc[i][c] + q[c];
        U2H ph;
        h2 t0; t0.x = (_Float16)w[0]; t0.y = (_Float16)w[1];
        h2 t1; t1.x = (_Float16)w[2]; t1.y = (_Float16)w[3];
        ph.h[0] = t0; ph.h[1] = t1;
        if (c0 < 64) *(uint2*)(xl2h + (size_t)n * OUTC + c0)      = ph.u;
        else         *(uint2*)(xr2h + (size_t)n * OUTC + c0 - 64) = ph.u;
    }
}

// ===== fused per-node edge kernels: degree-balanced, fdot2 logits =============
// layer 1: 1 wave/node (via perm), 4 edge-groups x 16 lanes; lane = 8 channels
__global__ __launch_bounds__(256) void k_node1(
        const int* __restrict__ perm,
        const int* __restrict__ rowptr, const int2* __restrict__ cedge,
        const float* __restrict__ easum,
        const _Float16* __restrict__ xlh, const _Float16* __restrict__ xrh,
        const _Float16* __restrict__ Weh, const _Float16* __restrict__ Ath,
        const float* __restrict__ bias, _Float16* __restrict__ h1h) {
    int slot = blockIdx.x * 4 + (threadIdx.x >> 6);
    if (slot >= NNODES) return;
    int n = perm[slot];
    int lane = threadIdx.x & 63;
    int g = lane >> 4;        // edge slot 0..3
    int q = lane & 15;        // channel oct; head = q>>2
    int c = q * 8;
    U4H xru; xru.u = *(const uint4*)(xrh + ((unsigned)n << 7) + c);
    U4H weu; weu.u = *(const uint4*)(Weh + c);
    U4H atu; atu.u = *(const uint4*)(Ath + c);   // att*log2e fp16
    h2 neg2; neg2.x = (_Float16)NEG; neg2.y = neg2.x;
    h2 zero; zero.x = (_Float16)0; zero.y = zero.x;
    h2 acc2[4] = { zero, zero, zero, zero };
    float s = 0.0f;
    int start = rowptr[n], deg = rowptr[n + 1] - start;

    // ---- self edge (prologue; only group 0 contributes) ----
    {
        U4H xss; xss.u = *(const uint4*)(xlh + ((unsigned)n << 7) + c);
        float amean = easum[0] * (1.0f / (float)NEDGES);
        h2 a2; a2.x = (_Float16)amean; a2.y = a2.x;
        float p = 0.0f;
        #pragma unroll
        for (int j = 0; j < 4; ++j) {
            h2 e = xss.h[j] + (a2 * weu.h[j] + xru.h[j]);
            h2 l = __builtin_elementwise_max(e, neg2 * e);
            p = FDOT2(l, atu.h[j], p);
        }
        p += __shfl_xor(p, 1, 64);
        p += __shfl_xor(p, 2, 64);
        if (g == 0) {
            float pe = exp2f(p);
            s += pe;
            h2 pe2; pe2.x = (_Float16)pe; pe2.y = pe2.x;
            #pragma unroll
            for (int j = 0; j < 4; ++j) acc2[j] += pe2 * xss.h[j];
        }
    }

    // ---- main loop: 8 edges/iter; descriptors prefetched 1 iter ahead ----
    if (deg > 0) {
        int dm1 = deg - 1;
        int2 epA = cedge[start + (g < dm1 ? g : dm1)];
        int2 epB = cedge[start + (4 + g < dm1 ? 4 + g : dm1)];
        for (int base = 0; base < deg; base += 8) {
            int2 cA = epA, cB = epB;
            int nxt = base + 8;
            if (nxt < deg) {
                int oA = nxt + g, oB = nxt + 4 + g;
                epA = cedge[start + (oA < dm1 ? oA : dm1)];
                epB = cedge[start + (oB < dm1 ? oB : dm1)];
            }
            U4H xA; xA.u = *(const uint4*)(xlh + ((unsigned)cA.x << 7) + c);
            U4H xB; xB.u = *(const uint4*)(xlh + ((unsigned)cB.x << 7) + c);
            // edge A
            {
                h2 a2; a2.x = (_Float16)__int_as_float(cA.y); a2.y = a2.x;
                float p = 0.0f;
                #pragma unroll
                for (int j = 0; j < 4; ++j) {
                    h2 e = xA.h[j] + (a2 * weu.h[j] + xru.h[j]);
                    h2 l = __builtin_elementwise_max(e, neg2 * e);
                    p = FDOT2(l, atu.h[j], p);
                }
                p += __shfl_xor(p, 1, 64);
                p += __shfl_xor(p, 2, 64);
                float pe = (base + g < deg) ? exp2f(p) : 0.0f;
                s += pe;
                h2 pe2; pe2.x = (_Float16)pe; pe2.y = pe2.x;
                #pragma unroll
                for (int j = 0; j < 4; ++j) acc2[j] += pe2 * xA.h[j];
            }
            // edge B
            {
                h2 a2; a2.x = (_Float16)__int_as_float(cB.y); a2.y = a2.x;
                float p = 0.0f;
                #pragma unroll
                for (int j = 0; j < 4; ++j) {
                    h2 e = xB.h[j] + (a2 * weu.h[j] + xru.h[j]);
                    h2 l = __builtin_elementwise_max(e, neg2 * e);
                    p = FDOT2(l, atu.h[j], p);
                }
                p += __shfl_xor(p, 1, 64);
                p += __shfl_xor(p, 2, 64);
                float pe = (base + 4 + g < deg) ? exp2f(p) : 0.0f;
                s += pe;
                h2 pe2; pe2.x = (_Float16)pe; pe2.y = pe2.x;
                #pragma unroll
                for (int j = 0; j < 4; ++j) acc2[j] += pe2 * xB.h[j];
            }
        }
    }
    // merge the 4 edge-groups (plain sums; softmax shift-free)
    #pragma unroll
    for (int off = 16; off <= 32; off <<= 1) {
        s += __shfl_xor(s, off, 64);
        #pragma unroll
        for (int j = 0; j < 4; ++j) {
            int lv = __builtin_bit_cast(int, acc2[j]);
            int t = __shfl_xor(lv, off, 64);
            acc2[j] += __builtin_bit_cast(h2, t);
        }
    }
    if (g == 0) {
        float inv = 1.0f / s;
        float4 bi0 = *(const float4*)(bias + c), bi1 = *(const float4*)(bias + c + 4);
        const float* bq = (const float*)&bi0;
        const float* br_ = (const float*)&bi1;
        float o[8];
        #pragma unroll
        for (int j = 0; j < 4; ++j) {
            o[2 * j]     = (float)acc2[j].x * inv + (j < 2 ? bq[2 * j]     : br_[2 * j - 4]);
            o[2 * j + 1] = (float)acc2[j].y * inv + (j < 2 ? bq[2 * j + 1] : br_[2 * j - 3]);
        }
        #pragma unroll
        for (int k = 0; k < 8; ++k) o[k] = o[k] > 0.0f ? o[k] : expm1f(o[k]);   // ELU
        U4H ph;
        #pragma unroll
        for (int k = 0; k < 4; ++k) {
            h2 t; t.x = (_Float16)o[2 * k]; t.y = (_Float16)o[2 * k + 1];
            ph.h[k] = t;
        }
        *(uint4*)(h1h + ((unsigned)n << 7) + c) = ph.u;
    }
}

// layer 2: 1 wave/node (via perm), 8 edge-groups x 8 lanes; lane = 8 channels
__global__ __launch_bounds__(256) void k_node2(
        const int* __restrict__ perm,
        const int* __restrict__ rowptr, const int2* __restrict__ cedge,
        const float* __restrict__ easum,
        const _Float16* __restrict__ xl2h, const _Float16* __restrict__ xr2h,
        const _Float16* __restrict__ Weh, const _Float16* __restrict__ Ath,
        const float* __restrict__ bias, float* __restrict__ out) {
    int slot = blockIdx.x * 4 + (threadIdx.x >> 6);
    if (slot >= NNODES) return;
    int n = perm[slot];
    int lane = threadIdx.x & 63;
    int g = lane >> 3;        // edge slot 0..7
    int q = lane & 7;         // channel oct
    int c = q * 8;
    U4H xru; xru.u = *(const uint4*)(xr2h + ((unsigned)n << 6) + c);
    U4H weu; weu.u = *(const uint4*)(Weh + c);
    U4H atu; atu.u = *(const uint4*)(Ath + c);
    h2 neg2; neg2.x = (_Float16)NEG; neg2.y = neg2.x;
    h2 zero; zero.x = (_Float16)0; zero.y = zero.x;
    h2 acc2[4] = { zero, zero, zero, zero };
    float s = 0.0f;
    int start = rowptr[n], deg = rowptr[n + 1] - start;

    // ---- self edge ----
    {
        U4H xss; xss.u = *(const uint4*)(xl2h + ((unsigned)n << 6) + c);
        float amean = easum[0] * (1.0f / (float)NEDGES);
        h2 a2; a2.x = (_Float16)amean; a2.y = a2.x;
        float p = 0.0f;
        #pragma unroll
        for (int j = 0; j < 4; ++j) {
            h2 e = xss.h[j] + (a2 * weu.h[j] + xru.h[j]);
            h2 l = __builtin_elementwise_max(e, neg2 * e);
            p = FDOT2(l, atu.h[j], p);
        }
        p += __shfl_xor(p, 1, 64);
        p += __shfl_xor(p, 2, 64);
        p += __shfl_xor(p, 4, 64);
        if (g == 0) {
            float pe = exp2f(p);
            s += pe;
            h2 pe2; pe2.x = (_Float16)pe; pe2.y = pe2.x;
            #pragma unroll
            for (int j = 0; j < 4; ++j) acc2[j] += pe2 * xss.h[j];
        }
    }

    // ---- main loop: 8 edges/iter; descriptors prefetched 1 iter ahead ----
    if (deg > 0) {
        int dm1 = deg - 1;
        int2 ep = cedge[start + (g < dm1 ? g : dm1)];
        for (int base = 0; base < deg; base += 8) {
            int2 cE = ep;
            int nxt = base + 8;
            if (nxt < deg) {
                int o = nxt + g;
                ep = cedge[start + (o < dm1 ? o : dm1)];
            }
            U4H xC; xC.u = *(const uint4*)(xl2h + ((unsigned)cE.x << 6) + c);
            h2 a2; a2.x = (_Float16)__int_as_float(cE.y); a2.y = a2.x;
            float p = 0.0f;
            #pragma unroll
            for (int j = 0; j < 4; ++j) {
                h2 e = xC.h[j] + (a2 * weu.h[j] + xru.h[j]);
                h2 l = __builtin_elementwise_max(e, neg2 * e);
                p = FDOT2(l, atu.h[j], p);
            }
            p += __shfl_xor(p, 1, 64);
            p += __shfl_xor(p, 2, 64);
            p += __shfl_xor(p, 4, 64);
            float pe = (base + g < deg) ? exp2f(p) : 0.0f;
            s += pe;
            h2 pe2; pe2.x = (_Float16)pe; pe2.y = pe2.x;
            #pragma unroll
            for (int j = 0; j < 4; ++j) acc2[j] += pe2 * xC.h[j];
        }
    }
    #pragma unroll
    for (int off = 8; off <= 32; off <<= 1) {
        s += __shfl_xor(s, off, 64);
        #pragma unroll
        for (int j = 0; j < 4; ++j) {
            int lv = __builtin_bit_cast(int, acc2[j]);
            int t = __shfl_xor(lv, off, 64);
            acc2[j] += __builtin_bit_cast(h2, t);
        }
    }
    if (g == 0) {
        float inv = 1.0f / s;
        float4 bi0 = *(const float4*)(bias + c), bi1 = *(const float4*)(bias + c + 4);
        const float* bq0 = (const float*)&bi0;
        const float* bq1 = (const float*)&bi1;
        float4 o0, o1;
        o0.x = (float)acc2[0].x * inv + bq0[0];  o0.y = (float)acc2[0].y * inv + bq0[1];
        o0.z = (float)acc2[1].x * inv + bq0[2];  o0.w = (float)acc2[1].y * inv + bq0[3];
        o1.x = (float)acc2[2].x * inv + bq1[0];  o1.y = (float)acc2[2].y * inv + bq1[1];
        o1.z = (float)acc2[3].x * inv + bq1[2];  o1.w = (float)acc2[3].y * inv + bq1[3];
        float4* op = (float4*)(out + (size_t)n * OUTC + c);
        op[0] = o0; op[1] = o1;
    }
}

extern "C" void kernel_launch(void* const* d_in, const int* in_sizes, int n_in,
                              void* d_out, int out_size, void* d_ws, size_t ws_size,
                              hipStream_t stream) {
    (void)in_sizes; (void)n_in; (void)out_size; (void)ws_size;
    const float* x    = (const float*)d_in[0];
    const int*   ei   = (const int*)d_in[1];
    const float* ea   = (const float*)d_in[2];
    const float* Wl1  = (const float*)d_in[3];
    const float* bl1  = (const float*)d_in[4];
    const float* Wr1  = (const float*)d_in[5];
    const float* br1  = (const float*)d_in[6];
    const float* We1  = (const float*)d_in[7];
    const float* att1 = (const float*)d_in[8];
    const float* b1   = (const float*)d_in[9];
    const float* Wl2  = (const float*)d_in[10];
    const float* bl2  = (const float*)d_in[11];
    const float* Wr2  = (const float*)d_in[12];
    const float* br2  = (const float*)d_in[13];
    const float* We2  = (const float*)d_in[14];
    const float* att2 = (const float*)d_in[15];
    const float* b2   = (const float*)d_in[16];
    float* out = (float*)d_out;

    // ---- workspace layout (bytes; every region 16B-aligned) ----
    char* wsb = (char*)d_ws;
    _Float16* xlh  = (_Float16*)wsb; wsb += (size_t)NNODES * HC1 * 2;   // 25.6 MB
    _Float16* xrh  = (_Float16*)wsb; wsb += (size_t)NNODES * HC1 * 2;
    _Float16* h1h  = (_Float16*)wsb; wsb += (size_t)NNODES * HC1 * 2;
    int2*   cedge  = (int2*)wsb;     wsb += (size_t)NEDGES * 8;         // 12.8 MB
    int*    erank  = (int*)wsb;      wsb += (size_t)NEDGES * 4;         // 6.4 MB
    int*    nrankp = (int*)wsb;      wsb += (size_t)NNODES * 4;
    int*    rowptr = (int*)wsb;      wsb += ((size_t)(NNODES + 4) * 4);
    int*    perm   = (int*)wsb;      wsb += (size_t)NNODES * 4;
    int*    csums  = (int*)wsb;      wsb += 512 * 4;
    float*  easpart= (float*)wsb;    wsb += (size_t)EBLK * 4;
    // --- contiguous zero-init region: cnt | bcnt ---
    int*    cnt    = (int*)wsb;      wsb += (size_t)NNODES * 4;
    int*    bcnt   = (int*)wsb;      wsb += 64 * 4;
    size_t  zbytes = (size_t)NNODES * 4 + 64 * 4;
    // ---
    int*    bbase  = (int*)wsb;      wsb += 64 * 4;
    float*  easum  = (float*)wsb;    wsb += 16;
    float*  Bt1    = (float*)wsb;    wsb += 20 * 256 * 4;
    float*  Bt2    = (float*)wsb;    wsb += 128 * 128 * 4;
    _Float16* Weh1 = (_Float16*)wsb; wsb += 128 * 2;
    _Float16* Ath1 = (_Float16*)wsb; wsb += 128 * 2;
    _Float16* Weh2 = (_Float16*)wsb; wsb += 64 * 2;
    _Float16* Ath2 = (_Float16*)wsb; wsb += 64 * 2;
    _Float16* xl2h = xlh;   // layer-2 tables reuse layer-1 storage
    _Float16* xr2h = xrh;

    hipMemsetAsync(cnt, 0, zbytes, stream);

    // ---- fused CSR build + prep (5 kernels) ----
    k_histsum<<<EBLK + PBLK, 256, 0, stream>>>(ei, ea, cnt, erank, easpart,
        Wl1, Wr1, Bt1, Wl2, Wr2, Bt2, We1, att1, Weh1, Ath1, We2, att2, Weh2, Ath2);
    k_scan_chunk<<<NCHUNK, 256, 0, stream>>>(cnt, rowptr, csums, bcnt, nrankp);
    k_scan_tops<<<1, 512, 0, stream>>>(csums, bcnt, bbase, easpart, easum);
    k_scan_add<<<NCHUNK, 256, 0, stream>>>(rowptr, csums, nrankp, bbase, perm);
    k_scatter<<<(NEDGES + 255) / 256, 256, 0, stream>>>(ei, ea, rowptr, erank, cedge);

    // ---- layer 1 ----
    k_gemm1<<<NBLK, 256, 0, stream>>>(x, Bt1, bl1, br1, xlh, xrh);
    k_node1<<<(NNODES + 3) / 4, 256, 0, stream>>>(perm, rowptr, cedge, easum,
                                                  xlh, xrh, Weh1, Ath1, b1, h1h);

    // ---- layer 2 ----
    k_gemm2<<<NBLK, 256, 0, stream>>>(h1h, Bt2, bl2, br2, xl2h, xr2h);
    k_node2<<<(NNODES + 3) / 4, 256, 0, stream>>>(perm, rowptr, cedge, easum,
                                                  xl2h, xr2h, Weh2, Ath2, b2, out);
}